// Round 7
// baseline (754.364 us; speedup 1.0000x reference)
//
#include <hip/hip_runtime.h>
#include <hip/hip_cooperative_groups.h>
#include <math.h>

namespace cg = cooperative_groups;

// ---------------- problem constants ----------------
#define NV    50257
#define OUT_M 402056            // 8*50257
#define OUT_A 402568            // + 8*64
#define SCALE 0.125f            // 1/sqrt(64)

// ---------------- ws layout (float offsets) ----------------
#define WS_Q      0             // [8][64][64]
#define WS_HTR    32768         // [1024][8]
#define WS_S      40960         // [64][64]
#define WS_TV     45056         // [64]
#define WS_C0     45120         // [1]
#define WS_HLIE   47144         // [8][64]
#define WS_W1     47656         // [8][64]
#define WS_GH     48176         // [8]
#define WS_WMAT   48192         // [8][64][64]
#define WS_SC     80960         // [8][256]
#define WS_WB     83008         // [8][64]
#define WS_CONSTB 83520         // [8]
#define WS_GAMMA  83528         // [8]
#define WS_CT     83536         // [8][64]
#define WS_P6     84048         // [8][4][20]
#define WS_PQT    86016         // [16][8][64]
#define WS_PHL    94208         // [16][8][64]
#define WS_PGH    102400        // [16][8]
#define WS_PGP    102528        // [32][8][64]
#define WS_PGG    118912        // [32][8]
#define WS_GL     131072        // [8][NV]

#define SM_FLOATS 9760          // 39040 B -> 4 blocks/CU co-resident

struct P {
    const float *h_t, *A_t, *G_t, *B_t, *E, *e_mask;
    const float *WG_w, *WG_b, *Sigma_inv, *WQ_w, *WQ_b, *WK_w;
    const float *WV_w, *WV_b, *WC_w, *WC_b, *WO_w;
    const float *wgamma_w, *wgamma_b, *wmu_w, *wmu_b, *gdown_w, *hlie_w, *hlie_b;
    float *ws, *out;
};

// ============================ phase bodies ============================

// ---- Gauss-Jordan (I-A)Q = (I+A) for batch b; writes WS_Q, WS_HTR ----
__device__ void d_gj(float* sm, const P& p, int b)
{
    const int tid = threadIdx.x;
    const int i  = tid & 63;
    const int cb = __builtin_amdgcn_readfirstlane(tid >> 6);
    float* A   = sm;            // [64][65]
    float* piv = sm + 4160;     // [2][132]
    float* fr  = sm + 4424;     // [2][64]
    float* dsh = sm + 4552;     // [64]
    for (int idx = tid; idx < 4096; idx += 256)
        A[(idx >> 6)*65 + (idx & 63)] = p.A_t[b*4096 + idx];
    for (int k = tid; k < 1024; k += 256)
        p.ws[WS_HTR + k*8 + b] = p.h_t[b*1024 + k];
    __syncthreads();
    float w[32];
    if (cb < 2) {
        #pragma unroll
        for (int jj = 0; jj < 32; ++jj) {
            int j = cb*32 + jj;
            w[jj] = (i == j ? 1.0f : 0.0f) - A[i*65 + j];
        }
    } else {
        #pragma unroll
        for (int jj = 0; jj < 32; ++jj) {
            int j = (cb - 2)*32 + jj;
            w[jj] = (i == j ? 1.0f : 0.0f) + A[i*65 + j];
        }
    }
    __syncthreads();
    #pragma unroll
    for (int k = 0; k < 64; ++k) {
        const int kb = k >> 5, sel = k & 1;
        if (cb == kb) fr[sel*64 + i] = w[k & 31];
        if (i == k) {
            #pragma unroll
            for (int q4 = 0; q4 < 8; ++q4)
                *(float4*)&piv[sel*132 + cb*32 + q4*4] =
                    make_float4(w[q4*4], w[q4*4+1], w[q4*4+2], w[q4*4+3]);
        }
        __syncthreads();
        float pk = piv[sel*132 + k];
        float f = (i == k) ? 0.0f : (fr[sel*64 + i] / pk);
        #pragma unroll
        for (int jj = 0; jj < 32; ++jj)
            w[jj] -= f * piv[sel*132 + cb*32 + jj];
    }
    if (cb == (i >> 5)) dsh[i] = w[i & 31];
    __syncthreads();
    if (cb >= 2) {
        float dinv = 1.0f / dsh[i];
        #pragma unroll
        for (int jj = 0; jj < 32; ++jj)
            A[i*65 + (cb - 2)*32 + jj] = w[jj] * dinv;   // A := Q
    }
    __syncthreads();
    for (int idx = tid; idx < 4096; idx += 256)
        p.ws[WS_Q + b*4096 + idx] = A[(idx >> 6)*65 + (idx & 63)];
    __syncthreads();
}

// ---- S = WG Sigma WG^T, tvec, c0 ----
__device__ void d_sphase(float* sm, const P& p)
{
    const int tid = threadIdx.x;
    const int a   = tid & 63;
    const int cb8 = __builtin_amdgcn_readfirstlane(tid >> 6);
    float* sig = sm;            // 64
    float* bg  = sm + 64;       // 64
    float* Wsc = sm + 128;      // [64][65]
    float* Wr  = sm + 4288;     // [64][65]
    if (tid < 64) { sig[tid] = p.Sigma_inv[tid]; bg[tid] = p.WG_b[tid]; }
    __syncthreads();
    for (int idx = tid; idx < 4096; idx += 256) {
        int r = idx >> 6, c = idx & 63;
        float wv = p.WG_w[idx];
        Wr[r*65 + c]  = wv;
        Wsc[r*65 + c] = wv * sig[c];
    }
    __syncthreads();
    float t8[16];
    #pragma unroll
    for (int j = 0; j < 16; ++j) t8[j] = 0.0f;
    for (int pp = 0; pp < 64; ++pp) {
        float wv = Wsc[a*65 + pp];
        #pragma unroll
        for (int jj = 0; jj < 16; ++jj)
            t8[jj] = fmaf(wv, Wr[(cb8*16 + jj)*65 + pp], t8[jj]);
    }
    #pragma unroll
    for (int jj = 0; jj < 16; ++jj)
        p.ws[WS_S + a*64 + cb8*16 + jj] = t8[jj];
    if (cb8 == 0) {
        float s = 0.0f;
        for (int pp = 0; pp < 64; ++pp) s += Wsc[a*65 + pp] * bg[pp];
        p.ws[WS_TV + a] = 2.0f * s;
    }
    if (tid == 0) {
        float c0 = 0.0f;
        for (int pp = 0; pp < 64; ++pp) c0 += sig[pp] * bg[pp] * bg[pp];
        p.ws[WS_C0] = c0;
    }
    __syncthreads();
}

// ---- h-GEMV partials, k-chunk c (WQ/hlie/wgamma read once) ----
__device__ void d_hgemv(float* sm, const P& p, int c)
{
    const int tid = threadIdx.x;
    const int i = tid & 63;
    const int w = __builtin_amdgcn_readfirstlane(tid >> 6);
    float* WQs = sm;            // [64][65]
    float* HLs = sm + 4160;     // [64][65]
    float* hh  = sm + 8320;     // [8][64]
    float* dd  = sm + 8832;     // [64]
    for (int idx = tid; idx < 4096; idx += 256) {
        int r = idx >> 6, col = idx & 63;
        int krow = c*64 + r;
        WQs[r*65 + col] = p.WQ_w[krow*64 + col];
        HLs[r*65 + col] = p.hlie_w[krow*64 + col];
    }
    for (int t = tid; t < 512; t += 256) {
        int b = t >> 6, kk = t & 63;
        hh[b*64 + kk] = p.h_t[b*1024 + c*64 + kk];
    }
    if (tid < 64) dd[tid] = p.wgamma_w[c*64 + tid];
    __syncthreads();
    const int b0 = 2*w, b1 = 2*w + 1;
    float q0 = 0, q1 = 0, l0 = 0, l1 = 0;
    #pragma unroll 8
    for (int kk = 0; kk < 64; ++kk) {
        float a = WQs[kk*65 + i], g = HLs[kk*65 + i];
        float h0 = hh[b0*64 + kk], h1 = hh[b1*64 + kk];
        q0 = fmaf(h0, a, q0); q1 = fmaf(h1, a, q1);
        l0 = fmaf(h0, g, l0); l1 = fmaf(h1, g, l1);
    }
    p.ws[WS_PQT + (c*8 + b0)*64 + i] = q0;
    p.ws[WS_PQT + (c*8 + b1)*64 + i] = q1;
    p.ws[WS_PHL + (c*8 + b0)*64 + i] = l0;
    p.ws[WS_PHL + (c*8 + b1)*64 + i] = l1;
    float g0 = hh[b0*64 + i] * dd[i];
    float g1 = hh[b1*64 + i] * dd[i];
    #pragma unroll
    for (int off = 32; off > 0; off >>= 1) {
        g0 += __shfl_xor(g0, off);
        g1 += __shfl_xor(g1, off);
    }
    if (i == 0) {
        p.ws[WS_PGH + c*8 + b0] = g0;
        p.ws[WS_PGH + c*8 + b1] = g1;
    }
    __syncthreads();
}

// ---- gdown partials, s-chunk c (gdown read once) ----
__device__ void d_gdown(float* sm, const P& p, int c)
{
    const int tid = threadIdx.x;
    const int i = tid & 63;
    const int w = __builtin_amdgcn_readfirstlane(tid >> 6);
    float* GD = sm;             // [63][65]
    float* hh = sm + 4160;      // [8][63]
    float* dd = sm + 4672;      // [63]
    for (int idx = tid; idx < 4032; idx += 256) {
        int r = idx >> 6, col = idx & 63;
        GD[r*65 + col] = p.gdown_w[(c*63 + r)*64 + col];
    }
    for (int t = tid; t < 504; t += 256) {
        int b = t / 63, sl = t % 63;
        int s = c*63 + sl;
        int i2 = 0, f = 0;
        while (f + (63 - i2) <= s) { f += 63 - i2; ++i2; }
        int j2 = i2 + 1 + (s - f);
        hh[b*63 + sl] = p.A_t[b*4096 + i2*64 + j2];
    }
    if (tid < 63) dd[tid] = p.wgamma_w[1088 + c*63 + tid];
    __syncthreads();
    const int b0 = 2*w, b1 = 2*w + 1;
    float a0 = 0, a1 = 0;
    #pragma unroll 4
    for (int sl = 0; sl < 63; ++sl) {
        float gd = GD[sl*65 + i];
        a0 = fmaf(hh[b0*63 + sl], gd, a0);
        a1 = fmaf(hh[b1*63 + sl], gd, a1);
    }
    p.ws[WS_PGP + (c*8 + b0)*64 + i] = a0;
    p.ws[WS_PGP + (c*8 + b1)*64 + i] = a1;
    float g0 = (i < 63) ? hh[b0*63 + i] * dd[i] : 0.0f;
    float g1 = (i < 63) ? hh[b1*63 + i] * dd[i] : 0.0f;
    #pragma unroll
    for (int off = 32; off > 0; off >>= 1) {
        g0 += __shfl_xor(g0, off);
        g1 += __shfl_xor(g1, off);
    }
    if (i == 0) {
        p.ws[WS_PGG + c*8 + b0] = g0;
        p.ws[WS_PGG + c*8 + b1] = g1;
    }
    __syncthreads();
}

// ---- kB: reduce partials -> qt/hl/gh; qkv -> ghl -> w1; W = Q G Q^T ----
__device__ void d_kB(float* sm, const P& p, int b)
{
    const int tid = threadIdx.x;
    const int i = tid & 63;
    const int cb = __builtin_amdgcn_readfirstlane(tid >> 6);
    const int col0 = cb * 16;
    float* Q     = sm;          // [64][65]
    float* G     = sm + 4160;   // [64][65]
    float* part  = sm + 8320;   // [4][64]
    float* partb = sm + 8576;   // [4][64]
    float* qt    = sm + 8832;   // 64
    float* hl    = sm + 8896;   // 64
    float* qkv   = sm + 8960;   // 64
    float* v0    = sm + 9024;   // 64
    float* r16   = sm + 9088;   // 16

    for (int idx = tid; idx < 4096; idx += 256) {
        int r = idx >> 6, c = idx & 63;
        Q[r*65 + c] = p.ws[WS_Q + b*4096 + idx];
        G[r*65 + c] = p.G_t[b*4096 + idx];
    }
    {
        float aq = 0, ah = 0;
        #pragma unroll
        for (int cc = 0; cc < 4; ++cc) {
            int c = cb*4 + cc;
            aq += p.ws[WS_PQT + (c*8 + b)*64 + i];
            ah += p.ws[WS_PHL + (c*8 + b)*64 + i];
        }
        part[cb*64 + i] = aq; partb[cb*64 + i] = ah;
    }
    if (tid < 16) r16[tid] = p.ws[WS_PGH + tid*8 + b];
    __syncthreads();
    if (tid < 64) {
        qt[tid] = part[tid]+part[64+tid]+part[128+tid]+part[192+tid] + p.WQ_b[tid];
        hl[tid] = partb[tid]+partb[64+tid]+partb[128+tid]+partb[192+tid] + p.hlie_b[tid];
    }
    if (tid == 0) {
        float s = 0;
        #pragma unroll
        for (int j = 0; j < 16; ++j) s += r16[j];
        p.ws[WS_GH + b] = s;
    }
    __syncthreads();
    {
        float acc = 0;
        #pragma unroll
        for (int jj = 0; jj < 16; ++jj)
            acc = fmaf(p.WK_w[i*64 + col0 + jj], qt[col0 + jj], acc);
        part[cb*64 + i] = acc;
    }
    __syncthreads();
    if (tid < 64) qkv[tid] = part[tid]+part[64+tid]+part[128+tid]+part[192+tid];
    __syncthreads();
    {
        float acc = 0;
        #pragma unroll
        for (int jj = 0; jj < 16; ++jj)
            acc = fmaf(G[i*65 + col0 + jj], hl[col0 + jj], acc);
        part[cb*64 + i] = acc;
    }
    __syncthreads();
    if (tid < 64)
        v0[tid] = SCALE*qkv[tid] + part[tid]+part[64+tid]+part[128+tid]+part[192+tid];
    __syncthreads();
    {
        float acc = 0;
        #pragma unroll
        for (int jj = 0; jj < 16; ++jj)
            acc = fmaf(Q[i*65 + col0 + jj], v0[col0 + jj], acc);
        part[cb*64 + i] = acc;
    }
    __syncthreads();
    if (tid < 64) {
        p.ws[WS_W1 + b*64 + tid]   = part[tid]+part[64+tid]+part[128+tid]+part[192+tid];
        p.ws[WS_HLIE + b*64 + tid] = hl[tid];
    }
    float tt[16];
    #pragma unroll
    for (int j = 0; j < 16; ++j) tt[j] = 0;
    for (int r = 0; r < 64; ++r) {
        float qv = Q[i*65 + r];
        #pragma unroll
        for (int j = 0; j < 16; ++j) tt[j] = fmaf(qv, G[r*65 + col0 + j], tt[j]);
    }
    __syncthreads();
    #pragma unroll
    for (int j = 0; j < 16; ++j) G[i*65 + col0 + j] = tt[j];   // G := T
    __syncthreads();
    float w2r[16];
    #pragma unroll
    for (int j = 0; j < 16; ++j) w2r[j] = 0;
    for (int q = 0; q < 64; ++q) {
        float tv = G[i*65 + q];
        #pragma unroll
        for (int j = 0; j < 16; ++j) w2r[j] = fmaf(tv, Q[(col0 + j)*65 + q], w2r[j]);
    }
    #pragma unroll
    for (int j = 0; j < 16; ++j)
        p.ws[WS_WMAT + b*4096 + (col0 + j)*64 + i] = w2r[j];
    __syncthreads();
}

// ---- kC: scores quarter (j = b*4 + q4) ----
__device__ void d_kC(float* sm, const P& p, int j)
{
    const int b = j >> 2, q4 = j & 3;
    const int tid = threadIdx.x, lane = tid & 63;
    const int gu = __builtin_amdgcn_readfirstlane(tid >> 6);
    const int col0 = gu * 16;
    float* B    = sm;           // [64][65]
    float* W    = sm + 4160;    // [64][64]
    float* w1   = sm + 8256;    // 64
    float* part = sm + 8320;    // [4][64]
    for (int idx = tid; idx < 4096; idx += 256) {
        int r = idx >> 6, c = idx & 63;
        B[r*65 + c] = p.B_t[b*16384 + (q4*64 + r)*64 + c];
        W[idx]      = p.ws[WS_WMAT + b*4096 + idx];
    }
    if (tid < 64) w1[tid] = p.ws[WS_W1 + b*64 + tid];
    __syncthreads();
    float t[16];
    #pragma unroll
    for (int jj = 0; jj < 16; ++jj) t[jj] = 0;
    for (int pp = 0; pp < 64; ++pp) {
        float bv = B[lane*65 + pp];
        #pragma unroll
        for (int jj = 0; jj < 16; ++jj) t[jj] = fmaf(bv, W[pp*64 + col0 + jj], t[jj]);
    }
    float ps = 0;
    #pragma unroll
    for (int jj = 0; jj < 16; ++jj)
        ps += (w1[col0+jj] - 0.5f*t[jj]) * B[lane*65 + col0 + jj];
    part[gu*64 + lane] = ps;
    __syncthreads();
    if (tid < 64)
        p.ws[WS_SC + b*256 + q4*64 + tid] =
            part[tid]+part[64+tid]+part[128+tid]+part[192+tid];
    __syncthreads();
}

// ---- kD: softmax, c chain, g_proj reduce, gamma, w_b ----
__device__ void d_kD(float* sm, const P& p, int b)
{
    const int tid = threadIdx.x, lane = tid & 63;
    const int gu = __builtin_amdgcn_readfirstlane(tid >> 6);
    const int col0 = gu * 16;
    const float* Qb = p.ws + WS_Q + b*4096;
    float* alpha = sm;          // 256
    float* rr    = sm + 256;    // 256
    float* part  = sm + 512;    // [4][64]
    float* cBr   = sm + 768;
    float* cB    = sm + 832;
    float* ct    = sm + 896;
    float* cw    = sm + 960;
    float* crot  = sm + 1024;
    float* gp    = sm + 1088;
    float* uv    = sm + 1152;
    float* red32 = sm + 1216;   // 32

    float sv = p.ws[WS_SC + b*256 + tid];
    rr[tid] = sv;
    if (tid < 32) red32[tid] = p.ws[WS_PGG + tid*8 + b];
    __syncthreads();
    for (int off = 128; off > 0; off >>= 1) { if (tid < off) rr[tid] = fmaxf(rr[tid], rr[tid+off]); __syncthreads(); }
    float smax = rr[0]; __syncthreads();
    float e = expf(sv - smax);
    rr[tid] = e; __syncthreads();
    for (int off = 128; off > 0; off >>= 1) { if (tid < off) rr[tid] += rr[tid+off]; __syncthreads(); }
    float den = rr[0]; __syncthreads();
    alpha[tid] = e / den;
    __syncthreads();
    {
        float acc = 0;
        for (int nn = 0; nn < 64; ++nn) {
            int n = gu*64 + nn;
            acc = fmaf(alpha[n], p.B_t[b*16384 + n*64 + lane], acc);
        }
        part[gu*64 + lane] = acc;
    }
    __syncthreads();
    if (tid < 64) cBr[tid] = part[tid]+part[64+tid]+part[128+tid]+part[192+tid];
    __syncthreads();
    {
        float acc = 0;
        #pragma unroll
        for (int pp = 0; pp < 16; ++pp) { int q = col0+pp; acc = fmaf(cBr[q], Qb[q*64+lane], acc); }
        part[gu*64 + lane] = acc;
    }
    __syncthreads();
    if (tid < 64) cB[tid] = part[tid]+part[64+tid]+part[128+tid]+part[192+tid];
    __syncthreads();
    {
        float acc = 0;
        #pragma unroll
        for (int pp = 0; pp < 16; ++pp) { int q = col0+pp; acc = fmaf(cB[q], p.WV_w[q*64+lane], acc); }
        part[gu*64 + lane] = acc;
    }
    __syncthreads();
    if (tid < 64) {
        float v = part[tid]+part[64+tid]+part[128+tid]+part[192+tid] + p.WV_b[tid];
        ct[tid] = v; p.ws[WS_CT + b*64 + tid] = v;
    }
    __syncthreads();
    {
        float acc = 0;
        #pragma unroll
        for (int pp = 0; pp < 16; ++pp) { int q = col0+pp; acc = fmaf(ct[q], p.WC_w[q*64+lane], acc); }
        part[gu*64 + lane] = acc;
    }
    __syncthreads();
    if (tid < 64) cw[tid] = part[tid]+part[64+tid]+part[128+tid]+part[192+tid] + p.WC_b[tid];
    __syncthreads();
    {
        float acc = 0;
        #pragma unroll
        for (int pp = 0; pp < 16; ++pp) { int q = col0+pp; acc = fmaf(cw[q], Qb[q*64+lane], acc); }
        part[gu*64 + lane] = acc;
    }
    __syncthreads();
    if (tid < 64) crot[tid] = part[tid]+part[64+tid]+part[128+tid]+part[192+tid];
    __syncthreads();
    {
        float acc = 0;
        #pragma unroll
        for (int cc = 0; cc < 8; ++cc) {
            int c = gu*8 + cc;
            acc += p.ws[WS_PGP + (c*8 + b)*64 + lane];
        }
        part[gu*64 + lane] = acc;
    }
    if (tid < 64) rr[64 + tid] = ct[tid] * p.wgamma_w[1024 + tid];
    __syncthreads();
    if (tid < 64) {
        float g = part[tid]+part[64+tid]+part[128+tid]+part[192+tid];
        gp[tid] = g; uv[tid] = 2.0f * p.Sigma_inv[tid] * g;
    }
    if (tid == 0) {
        float gc = 0;
        for (int j = 0; j < 64; ++j) gc += rr[64 + j];
        float ga = 0;
        for (int j = 0; j < 32; ++j) ga += red32[j];
        float z = p.ws[WS_GH + b] + gc + ga + p.wgamma_b[0];
        p.ws[WS_GAMMA + b] = 1.0f / (1.0f + expf(-z));
    }
    __syncthreads();
    {
        float acc = 0;
        #pragma unroll
        for (int pp = 0; pp < 16; ++pp) { int q = col0+pp; acc = fmaf(p.WG_w[lane*64+q], uv[q], acc); }
        part[gu*64 + lane] = acc;
    }
    if (tid < 64) rr[tid] = p.WG_b[tid]*uv[tid] - gp[tid]*gp[tid]*p.Sigma_inv[tid];
    __syncthreads();
    if (tid < 64)
        p.ws[WS_WB + b*64 + tid] = SCALE*crot[tid]
            + part[tid]+part[64+tid]+part[128+tid]+part[192+tid];
    if (tid == 0) { float s = 0; for (int j = 0; j < 64; ++j) s += rr[j]; p.ws[WS_CONSTB + b] = s; }
    __syncthreads();
}

// ---- k5a: group-logit quadratic; 64 v per chunk ----
// persistent: S 4096 | tv 64 | wb 512 | gm 8 | cb 8  (ends 4688)
// per chunk:  E [64][66] @4688 | sv [4][64] @8912 | gd [64][9] @9168 (ends 9744)
__device__ void d_k5a_persist(float* sm, const P& p)
{
    const int tid = threadIdx.x;
    for (int idx = tid; idx < 4096; idx += 256) sm[idx] = p.ws[WS_S + idx];
    if (tid < 64) sm[4096 + tid] = p.ws[WS_TV + tid];
    for (int idx = tid; idx < 512; idx += 256) sm[4160 + idx] = p.ws[WS_WB + idx];
    if (tid < 8) {
        sm[4672 + tid] = p.ws[WS_GAMMA + tid];
        sm[4680 + tid] = p.ws[WS_CONSTB + tid];
    }
}

__device__ void d_k5a_chunk(float* sm, const P& p, int c)
{
    const int tid = threadIdx.x;
    const int vt = tid & 63;
    const int q  = __builtin_amdgcn_readfirstlane(tid >> 6);
    const int vb = c * 64;
    const int v  = vb + vt;
    const bool vok = v < NV;
    float* S  = sm;
    float* tv = sm + 4096;
    float* wb = sm + 4160;
    float* gm = sm + 4672;
    float* cbs= sm + 4680;
    float* E  = sm + 4688;      // [64][66]
    float* svs= sm + 8912;      // [4][64]
    float* gds= sm + 9168;      // [64][9]

    for (int idx = tid; idx < 1024; idx += 256) {
        int r = idx >> 4, c4 = (idx & 15) * 4;
        int vr = vb + r; if (vr >= NV) vr = NV - 1;
        float4 e4 = *(const float4*)(p.E + (size_t)vr * 64 + c4);
        float* dst = E + r*66 + c4;
        dst[0] = e4.x; dst[1] = e4.y; dst[2] = e4.z; dst[3] = e4.w;
    }
    __syncthreads();
    {
        const float* er = E + vt*66;
        float sv = (q == 0) ? p.ws[WS_C0] : 0.0f;
        float t[16];
        #pragma unroll
        for (int j = 0; j < 16; ++j) t[j] = 0.0f;
        for (int pp = 0; pp < 64; ++pp) {
            float ep = er[pp];
            #pragma unroll
            for (int j = 0; j < 16; ++j)
                t[j] = fmaf(ep, S[pp*64 + q*16 + j], t[j]);
        }
        #pragma unroll
        for (int j = 0; j < 16; ++j)
            sv += (t[j] + tv[q*16 + j]) * er[q*16 + j];
        svs[q*64 + vt] = sv;
        const float* w0 = wb + (2*q    )*64;
        const float* w1 = wb + (2*q + 1)*64;
        float g0 = 0, g1 = 0;
        #pragma unroll 8
        for (int pp = 0; pp < 64; ++pp) {
            float ep = er[pp];
            g0 = fmaf(ep, w0[pp], g0); g1 = fmaf(ep, w1[pp], g1);
        }
        gds[vt*9 + 2*q]     = g0;
        gds[vt*9 + 2*q + 1] = g1;
    }
    __syncthreads();
    if (q == 0 && vok) {
        float svt = svs[vt] + svs[64+vt] + svs[128+vt] + svs[192+vt];
        const float* gr = gds + vt*9;
        #pragma unroll
        for (int bb = 0; bb < 8; ++bb)
            p.ws[WS_GL + bb*NV + v] = gm[bb] * (gr[bb] + cbs[bb] - svt);
    }
}

// ---- k5b: WO stream; 64 v per chunk, 4-way wave-uniform k-split ----
// persistent: hsh 8192 | per chunk: red [3][64][8] @8192 (ends 9728)
__device__ void d_k5b_persist(float* sm, const P& p)
{
    const int tid = threadIdx.x;
    for (int idx = tid; idx < 2048; idx += 256)
        *(float4*)(sm + idx*4) = *(const float4*)(p.ws + WS_HTR + idx*4);
}

__device__ void d_k5b_chunk(float* sm, const P& p, int c)
{
    const int tid = threadIdx.x;
    const int vt = tid & 63;
    const int kg = __builtin_amdgcn_readfirstlane(tid >> 6);   // 0..3
    const int vb = c * 64;
    const int v  = vb + vt;
    const bool vok = v < NV;
    const int vv = vok ? v : NV - 1;
    float* h   = sm;
    float* red = sm + 8192;

    float acc[8];
    #pragma unroll
    for (int bb = 0; bb < 8; ++bb) acc[bb] = 0.0f;
    {
        const float* wo = p.WO_w + (size_t)(kg * 256) * NV + vv;
        const float* hb = h + kg*256*8;
        for (int k0 = 0; k0 < 256; k0 += 8) {
            float wr[8];
            #pragma unroll
            for (int u = 0; u < 8; ++u) wr[u] = wo[(size_t)(k0 + u) * NV];
            #pragma unroll
            for (int u = 0; u < 8; ++u) {
                const float* hp = hb + (k0 + u)*8;
                #pragma unroll
                for (int bb = 0; bb < 8; ++bb) acc[bb] = fmaf(hp[bb], wr[u], acc[bb]);
            }
        }
    }
    float gl[8];
    if (kg == 0) {
        #pragma unroll
        for (int bb = 0; bb < 8; ++bb) gl[bb] = p.ws[WS_GL + bb*NV + vv];
    }
    __syncthreads();
    if (kg >= 1) {
        float* r = red + (kg - 1)*512 + vt*8;
        #pragma unroll
        for (int bb = 0; bb < 8; ++bb) r[bb] = acc[bb];
    }
    __syncthreads();
    if (kg == 0 && vok) {
        #pragma unroll
        for (int bb = 0; bb < 8; ++bb)
            p.out[bb*NV + v] = acc[bb] + red[vt*8+bb] + red[512+vt*8+bb]
                             + red[1024+vt*8+bb] + gl[bb];
    }
}

// ---- k6a: per (b, quarter) top-8 + online softmax sums ----
#define NQ 12565
__device__ void d_k6a(float* sm, const P& p, int j)
{
    const int b = j >> 2, qq = j & 3;
    const int tid = threadIdx.x, lane = tid & 63, wvi = tid >> 6;
    const int v0 = qq * NQ;
    const int v1 = (v0 + NQ < NV) ? (v0 + NQ) : NV;
    const float* lg = p.out + b*NV;
    float* mvw = sm;                 // [4][8]
    int*   miw = (int*)(sm + 32);    // [4][8]
    float* t8v = sm + 64;            // [8]
    int*   t8i = (int*)(sm + 72);    // [8]
    float* redv= sm + 80;            // [4]
    float* sred= sm + 84;            // [4]

    float lv[8]; int li[8];
    #pragma unroll
    for (int u = 0; u < 8; ++u) { lv[u] = -INFINITY; li[u] = 0x7fffffff; }
    float mt = -INFINITY, s1 = 0.0f, s2 = 0.0f;
    for (int v = v0 + tid; v < v1; v += 256) {
        float x = lg[v];
        if (x > mt) {
            float r = expf(mt - x);
            s1 *= r; s2 *= r; mt = x;
        }
        float ee = expf(x - mt);
        s1 += ee; s2 += x * ee;
        if (x > lv[7]) {
            float cv = x; int ci = v;
            #pragma unroll
            for (int u = 0; u < 8; ++u) {
                if (cv > lv[u]) {
                    float tv2 = lv[u]; lv[u] = cv; cv = tv2;
                    int   ti = li[u]; li[u] = ci; ci = ti;
                }
            }
        }
    }
    float wv8[8]; int wi8[8];
    #pragma unroll
    for (int it = 0; it < 8; ++it) {
        float bv = lv[0]; int bi = li[0];
        #pragma unroll
        for (int off = 32; off > 0; off >>= 1) {
            float ov = __shfl_xor(bv, off);
            int   oi = __shfl_xor(bi, off);
            if (ov > bv || (ov == bv && oi < bi)) { bv = ov; bi = oi; }
        }
        wv8[it] = bv; wi8[it] = bi;
        if (lv[0] == bv && li[0] == bi) {
            lv[0]=lv[1]; lv[1]=lv[2]; lv[2]=lv[3]; lv[3]=lv[4];
            lv[4]=lv[5]; lv[5]=lv[6]; lv[6]=lv[7]; lv[7]=-INFINITY;
            li[0]=li[1]; li[1]=li[2]; li[2]=li[3]; li[3]=li[4];
            li[4]=li[5]; li[5]=li[6]; li[6]=li[7]; li[7]=0x7fffffff;
        }
    }
    if (lane == 0) {
        #pragma unroll
        for (int u = 0; u < 8; ++u) { mvw[wvi*8 + u] = wv8[u]; miw[wvi*8 + u] = wi8[u]; }
    }
    __syncthreads();
    if (tid == 0) {
        int pA = 0, pB = 0, pC = 0, pD = 0;
        for (int it = 0; it < 8; ++it) {
            float vA = mvw[0*8+pA], vB = mvw[1*8+pB], vC = mvw[2*8+pC], vD = mvw[3*8+pD];
            int   iA = miw[0*8+pA], iB = miw[1*8+pB], iC = miw[2*8+pC], iD = miw[3*8+pD];
            float best = vA; int bi = iA; int w = 0;
            if (vB > best || (vB == best && iB < bi)) { best = vB; bi = iB; w = 1; }
            if (vC > best || (vC == best && iC < bi)) { best = vC; bi = iC; w = 2; }
            if (vD > best || (vD == best && iD < bi)) { best = vD; bi = iD; w = 3; }
            t8v[it] = best; t8i[it] = bi;
            if (w == 0) ++pA; else if (w == 1) ++pB; else if (w == 2) ++pC; else ++pD;
        }
    }
    __syncthreads();
    float Mp = t8v[0];
    {
        float r = expf(mt - Mp);
        s1 *= r; s2 *= r;
    }
    #pragma unroll
    for (int off = 32; off > 0; off >>= 1) {
        s1 += __shfl_xor(s1, off);
        s2 += __shfl_xor(s2, off);
    }
    if (lane == 0) { redv[wvi] = s1; sred[wvi] = s2; }
    __syncthreads();
    if (tid == 0) {
        int base = WS_P6 + (b*4 + qq)*20;
        #pragma unroll
        for (int u = 0; u < 8; ++u) { p.ws[base + u] = t8v[u]; ((int*)p.ws)[base + 8 + u] = t8i[u]; }
        p.ws[base + 16] = Mp;
        p.ws[base + 17] = redv[0]+redv[1]+redv[2]+redv[3];
        p.ws[base + 18] = sred[0]+sred[1]+sred[2]+sred[3];
    }
    __syncthreads();
}

// ---- k6b: merge partials, H, E_exp, rho, mu, m_next, A_next ----
__device__ void d_k6b(float* sm, const P& p, int b)
{
    const int tid = threadIdx.x;
    float* mv   = sm;                // 32
    int*   mi   = (int*)(sm + 32);   // 32
    float* t8v  = sm + 64;           // 8
    int*   t8i  = (int*)(sm + 72);   // 8
    float* topp = sm + 80;           // 8
    float* scal = sm + 88;           // 4
    float* uvec = sm + 96;           // 64
    float* eexp = sm + 160;          // 64
    float* msh  = sm + 224;          // 64
    float* emsh = sm + 288;          // 64
    float* redv = sm + 352;          // 256

    if (tid < 32) {
        int base = WS_P6 + (b*4 + (tid >> 3))*20;
        mv[tid] = p.ws[base + (tid & 7)];
        mi[tid] = ((const int*)p.ws)[base + 8 + (tid & 7)];
    }
    __syncthreads();
    if (tid == 0) {
        unsigned used = 0;
        for (int it = 0; it < 8; ++it) {
            float best = -INFINITY; int bi = 0x7fffffff, bs = 0;
            for (int c = 0; c < 32; ++c) {
                if (used & (1u << c)) continue;
                float x = mv[c];
                if (x > best || (x == best && mi[c] < bi)) { best = x; bi = mi[c]; bs = c; }
            }
            used |= 1u << bs; t8v[it] = best; t8i[it] = bi;
        }
        float M = t8v[0];
        float s1 = 0, s2 = 0;
        for (int q = 0; q < 4; ++q) {
            int base = WS_P6 + (b*4 + q)*20;
            float sc_ = expf(p.ws[base + 16] - M);
            s1 += p.ws[base + 17] * sc_; s2 += p.ws[base + 18] * sc_;
        }
        scal[0] = M + logf(s1) - s2 / s1;       // H
        float ts = 0, tv_[8];
        #pragma unroll
        for (int u = 0; u < 8; ++u) { tv_[u] = expf(t8v[u] - M); ts += tv_[u]; }
        #pragma unroll
        for (int u = 0; u < 8; ++u) topp[u] = tv_[u] / ts;
    }
    __syncthreads();
    if (tid < 64) {
        float u_ = 0;
        #pragma unroll
        for (int j = 0; j < 8; ++j) u_ += topp[j] * p.E[t8i[j]*64 + tid];
        uvec[tid] = u_;
    }
    __syncthreads();
    if (tid < 64) {
        const float* Qb = p.ws + WS_Q + b*4096;
        float a = 0;
        for (int pp = 0; pp < 64; ++pp) a += uvec[pp] * Qb[pp*64 + tid];
        eexp[tid] = a;
    }
    __syncthreads();
    {
        const float* Gb = p.G_t + b*4096;
        const float* HL = p.ws + WS_HLIE + b*64;
        float a = 0;
        #pragma unroll 4
        for (int t2 = 0; t2 < 16; ++t2) {
            int idx = tid*16 + t2;
            int pp = idx >> 6, q = idx & 63;
            a += (eexp[pp] - HL[pp]) * Gb[idx] * (eexp[q] - HL[q]);
        }
        redv[tid] = a;
    }
    __syncthreads();
    for (int off = 128; off > 0; off >>= 1) {
        if (tid < off) redv[tid] += redv[tid + off];
        __syncthreads();
    }
    if (tid == 0) scal[1] = redv[0];
    __syncthreads();
    float pm = 0;
    for (int k = tid; k < 1024; k += 256) pm += p.h_t[b*1024 + k] * p.wmu_w[k];
    if (tid < 64) pm += p.ws[WS_CT + b*64 + tid] * p.wmu_w[1024 + tid];
    redv[tid] = pm;
    __syncthreads();
    for (int off = 128; off > 0; off >>= 1) {
        if (tid < off) redv[tid] += redv[tid + off];
        __syncthreads();
    }
    if (tid == 0) {
        float z = redv[0] + scal[0]*p.wmu_w[1088] + scal[1]*p.wmu_w[1089] + p.wmu_b[0];
        scal[2] = 1.0f / (1.0f + expf(-z));
    }
    __syncthreads();
    if (tid < 64) {
        float mu = scal[2];
        float em = p.e_mask[b*64 + tid];
        float m = mu*em + (1.0f - mu)*eexp[tid];
        p.out[OUT_M + b*64 + tid] = m;
        msh[tid] = m; emsh[tid] = em;
    }
    __syncthreads();
    for (int idx = tid; idx < 4096; idx += 256) {
        int i = idx >> 6, j = idx & 63;
        p.out[OUT_A + b*4096 + idx] = p.A_t[b*4096 + idx]
            + 0.1f*(msh[i]*emsh[j] - msh[j]*emsh[i]);
    }
    __syncthreads();
}

// ============================ mega kernel (cooperative) ============================
__global__ __launch_bounds__(256) void mega(P p)
{
    __shared__ float sm[SM_FLOATS];
    cg::grid_group g = cg::this_grid();
    const int blk = blockIdx.x, gdim = gridDim.x;

    for (int j = blk; j < 57; j += gdim) {
        if (j < 8)       d_gj(sm, p, j);
        else if (j == 8) d_sphase(sm, p);
        else if (j < 25) d_hgemv(sm, p, j - 9);
        else             d_gdown(sm, p, j - 25);
    }
    g.sync();
    for (int j = blk; j < 8;  j += gdim) d_kB(sm, p, j);
    g.sync();
    for (int j = blk; j < 32; j += gdim) d_kC(sm, p, j);
    g.sync();
    for (int j = blk; j < 8;  j += gdim) d_kD(sm, p, j);
    g.sync();
    d_k5a_persist(sm, p); __syncthreads();
    for (int c = blk; c < 786; c += gdim) d_k5a_chunk(sm, p, c);
    g.sync();
    d_k5b_persist(sm, p); __syncthreads();
    for (int c = blk; c < 786; c += gdim) d_k5b_chunk(sm, p, c);
    g.sync();
    for (int j = blk; j < 32; j += gdim) d_k6a(sm, p, j);
    g.sync();
    for (int j = blk; j < 8;  j += gdim) d_k6b(sm, p, j);
}

// ============================ fallback standalone kernels ============================
__global__ __launch_bounds__(256) void kA_prep(P p)
{
    __shared__ float sm[SM_FLOATS];
    int j = blockIdx.x;
    if (j < 8)       d_gj(sm, p, j);
    else if (j == 8) d_sphase(sm, p);
    else if (j < 25) d_hgemv(sm, p, j - 9);
    else             d_gdown(sm, p, j - 25);
}
__global__ __launch_bounds__(256) void kB_k(P p)
{
    __shared__ float sm[SM_FLOATS];
    d_kB(sm, p, blockIdx.x);
}
__global__ __launch_bounds__(256) void kC_k(P p)
{
    __shared__ float sm[SM_FLOATS];
    d_kC(sm, p, blockIdx.x);
}
__global__ __launch_bounds__(256) void kD_k(P p)
{
    __shared__ float sm[SM_FLOATS];
    d_kD(sm, p, blockIdx.x);
}
__global__ __launch_bounds__(256) void k5a_k(P p)
{
    __shared__ float sm[SM_FLOATS];
    d_k5a_persist(sm, p); __syncthreads();
    for (int c = blockIdx.x; c < 786; c += gridDim.x) d_k5a_chunk(sm, p, c);
}
__global__ __launch_bounds__(256) void k5b_k(P p)
{
    __shared__ float sm[SM_FLOATS];
    d_k5b_persist(sm, p); __syncthreads();
    for (int c = blockIdx.x; c < 786; c += gridDim.x) d_k5b_chunk(sm, p, c);
}
__global__ __launch_bounds__(256) void k6a_k(P p)
{
    __shared__ float sm[SM_FLOATS];
    d_k6a(sm, p, blockIdx.x);
}
__global__ __launch_bounds__(256) void k6b_k(P p)
{
    __shared__ float sm[SM_FLOATS];
    d_k6b(sm, p, blockIdx.x);
}

// ============================ launch ============================
extern "C" void kernel_launch(void* const* d_in, const int* in_sizes, int n_in,
                              void* d_out, int out_size, void* d_ws, size_t ws_size,
                              hipStream_t stream)
{
    P p;
    p.h_t      = (const float*)d_in[0];
    p.A_t      = (const float*)d_in[1];
    p.B_t      = (const float*)d_in[2];
    p.E        = (const float*)d_in[3];
    p.e_mask   = (const float*)d_in[4];
    p.G_t      = (const float*)d_in[5];
    p.WQ_w     = (const float*)d_in[7];
    p.WQ_b     = (const float*)d_in[8];
    p.WK_w     = (const float*)d_in[9];
    p.WV_w     = (const float*)d_in[11];
    p.WV_b     = (const float*)d_in[12];
    p.WC_w     = (const float*)d_in[13];
    p.WC_b     = (const float*)d_in[14];
    p.WO_w     = (const float*)d_in[15];
    p.WG_w     = (const float*)d_in[16];
    p.WG_b     = (const float*)d_in[17];
    p.wgamma_w = (const float*)d_in[18];
    p.wgamma_b = (const float*)d_in[19];
    p.wmu_w    = (const float*)d_in[20];
    p.wmu_b    = (const float*)d_in[21];
    p.gdown_w  = (const float*)d_in[22];
    p.Sigma_inv= (const float*)d_in[23];
    p.hlie_w   = (const float*)d_in[24];
    p.hlie_b   = (const float*)d_in[25];
    p.ws  = (float*)d_ws;
    p.out = (float*)d_out;

    // Try single cooperative launch (kills 7 inter-kernel launch gaps).
    int maxB = 0;
    hipError_t e = hipOccupancyMaxActiveBlocksPerMultiprocessor(
        &maxB, (const void*)mega, 256, 0);
    bool done = false;
    if (e == hipSuccess && maxB >= 1) {
        int nblk = maxB * 256;               // 256 CUs on MI355X
        if (nblk > 1024) nblk = 1024;
        void* args[] = { (void*)&p };
        e = hipLaunchCooperativeKernel((const void*)mega, dim3(nblk),
                                       dim3(256, 1, 1), args, 0, stream);
        if (e == hipSuccess) done = true;
    }
    if (!done) {
        // Fallback: proven 8-launch path (same device-function bodies).
        kA_prep<<<57,  256, 0, stream>>>(p);
        kB_k  <<<8,   256, 0, stream>>>(p);
        kC_k  <<<32,  256, 0, stream>>>(p);
        kD_k  <<<8,   256, 0, stream>>>(p);
        k5a_k <<<786, 256, 0, stream>>>(p);
        k5b_k <<<786, 256, 0, stream>>>(p);
        k6a_k <<<32,  256, 0, stream>>>(p);
        k6b_k <<<8,   256, 0, stream>>>(p);
    }
}